// Round 12
// baseline (1350.554 us; speedup 1.0000x reference)
//
#include <hip/hip_runtime.h>

// y = alpha*(x @ Q^T) + bias; alpha = mean|W|; Q = clip(round(W/alpha),-1,1)
// x:(2,4096,4096) f32, W:(16384,4096) f32, bias:(16384) f32, out f32.
#define M_DIM 8192
#define N_DIM 16384
#define K_DIM 4096
#define NT 128  // K_DIM / 32

typedef unsigned short u16;
typedef unsigned int u32;
typedef __attribute__((ext_vector_type(8))) short bf16x8;
typedef __attribute__((ext_vector_type(8))) unsigned short u16x8;
typedef __attribute__((ext_vector_type(4))) float f32x4;

#define MFMA(a, b, c) __builtin_amdgcn_mfma_f32_16x16x32_bf16(a, b, c, 0, 0, 0)
#define SGB(mask, n) __builtin_amdgcn_sched_group_barrier((mask), (n), 0)

__device__ __forceinline__ void gload16(const u16* g, u16* l) {
  __builtin_amdgcn_global_load_lds((const __attribute__((address_space(1))) void*)g,
                                   (__attribute__((address_space(3))) void*)l, 16, 0, 0);
}

// ---------------- alpha = mean(|W|), f64 two-pass reduction ----------------
__global__ void reduce_abs1(const float* __restrict__ w, double* __restrict__ partials) {
  const float4* w4 = (const float4*)w;
  size_t base = (size_t)blockIdx.x * 4096 + threadIdx.x;
  double s = 0.0;
#pragma unroll
  for (int i = 0; i < 16; ++i) {
    float4 v = w4[base + (size_t)i * 256];
    s += (double)fabsf(v.x); s += (double)fabsf(v.y);
    s += (double)fabsf(v.z); s += (double)fabsf(v.w);
  }
#pragma unroll
  for (int off = 32; off > 0; off >>= 1) s += __shfl_down(s, off, 64);
  __shared__ double red[4];
  int wv = threadIdx.x >> 6, lane = threadIdx.x & 63;
  if (lane == 0) red[wv] = s;
  __syncthreads();
  if (threadIdx.x == 0) partials[blockIdx.x] = (red[0] + red[1]) + (red[2] + red[3]);
}

__global__ void reduce_abs2(const double* __restrict__ partials,
                            double* __restrict__ alpha_d, float* __restrict__ alpha_f) {
  double s = 0.0;
  for (int i = threadIdx.x; i < 4096; i += 256) s += partials[i];
#pragma unroll
  for (int off = 32; off > 0; off >>= 1) s += __shfl_down(s, off, 64);
  __shared__ double red[4];
  int wv = threadIdx.x >> 6, lane = threadIdx.x & 63;
  if (lane == 0) red[wv] = s;
  __syncthreads();
  if (threadIdx.x == 0) {
    double total = (red[0] + red[1]) + (red[2] + red[3]);
    double a = total / (double)((long long)N_DIM * (long long)K_DIM);
    alpha_d[0] = a;
    alpha_f[0] = (float)a;
  }
}

// ---------------- W -> ternary Q stored as bf16 (+1/0/-1 exact) ----------------
__global__ void quant_w(const float* __restrict__ w, const double* __restrict__ alpha_d,
                        u16* __restrict__ q) {
  double inv = 1.0 / alpha_d[0];
  size_t i8 = (size_t)blockIdx.x * 256 + threadIdx.x;
  const float4* w4 = (const float4*)w;
  float4 v0 = w4[i8 * 2], v1 = w4[i8 * 2 + 1];
  float vv[8] = {v0.x, v0.y, v0.z, v0.w, v1.x, v1.y, v1.z, v1.w};
  u16x8 o;
#pragma unroll
  for (int j = 0; j < 8; ++j) {
    double r = rint((double)vv[j] * inv);
    u16 enc = 0;
    if (r >= 1.0) enc = 0x3F80u;
    else if (r <= -1.0) enc = 0xBF80u;
    o[j] = enc;
  }
  *((u16x8*)q + i8) = o;
}

// ---------------- x fp32 -> bf16 (RNE) ----------------
__global__ void conv_x(const float* __restrict__ x, u16* __restrict__ xb) {
  size_t i8 = (size_t)blockIdx.x * 256 + threadIdx.x;
  const float4* x4 = (const float4*)x;
  float4 v0 = x4[i8 * 2], v1 = x4[i8 * 2 + 1];
  float vv[8] = {v0.x, v0.y, v0.z, v0.w, v1.x, v1.y, v1.z, v1.w};
  u16x8 o;
#pragma unroll
  for (int j = 0; j < 8; ++j) {
    u32 u = __float_as_uint(vv[j]);
    u += 0x7FFFu + ((u >> 16) & 1u);
    o[j] = (u16)(u >> 16);
  }
  *((u16x8*)xb + i8) = o;
}

// --- 256x256-tile bf16 GEMM: BK=32 ring-4, counted vmcnt, FRAG-PACKED LDS ---
// R11 structure verbatim; single change: LDS layout. R11's BK=32 XOR swizzle
// had 4-way read conflicts (64B row stride = 16 banks; SQ_LDS_BANK_CONFLICT
// 1.007e8 ~= 16% of runtime). Frag-packed layout (R9/m173, measured 0
// conflicts): chunk (subtile m, lane l) at linear (m*64+l)*16B holds global
// [row=m*16+(l&15)][k=((l>>4)&3)*8] -> every ds_read_b128 is wave-uniform
// base + l*16B, a contiguous 1KB access: conflict-free by construction.
// Permutation lives in the per-lane GLOBAL source offsets of global_load_lds
// (LDS dest stays linear). T4 counted vmcnt(8) per tile end kept (ring-4,
// stage g+3, never drains); SGB batches kept; no setprio (R10 -7%).
__global__ __launch_bounds__(512, 2) void gemm256(
    const u16* __restrict__ A, const u16* __restrict__ Bq,
    const float* __restrict__ bias, const float* __restrict__ alpha_f,
    float* __restrict__ C) {
  __shared__ __align__(16) u16 Alds[4][256 * 32];  // 16 KiB per ring buffer
  __shared__ __align__(16) u16 Blds[4][256 * 32];

  const int t = threadIdx.x;
  const int wv = t >> 6, l = t & 63;
  const int wr = wv >> 2, wc = wv & 3;  // 2M x 4N wave grid
  const int lr = l & 15, lk = l >> 4;
  const int l8 = l * 8;  // u16 units: lane slot within a frag chunk

  // XCD-bijective swizzle (2048 % 8 == 0) + 8(tm) x 64(tn) supertiles
  const int bid = blockIdx.x;
  const int wg = (bid & 7) * 256 + (bid >> 3);
  const int grp = wg >> 9, rem = wg & 511;
  const int tm = grp * 8 + (rem & 7);  // 0..31
  const int tn = rem >> 3;             // 0..63

  const u16* Ag = A + (size_t)tm * 256 * K_DIM;
  const u16* Bg = Bq + (size_t)tn * 256 * K_DIM;

  // Staging (frag-packed): chunk q in [0,1024) = (m = q>>6, lane = q&63);
  // holds global [row = m*16 + (q&15)][k = ((q>>4)&3)*8 .. +8).
  // Thread t owns q = t and q = 512 + t. LDS dest = linear chunk order
  // (wave-uniform base + lane*16B); permutation is in the source offset.
  int so[2], dof[2];
#pragma unroll
  for (int s = 0; s < 2; ++s) {
    int q = s * 512 + t;
    int row = (q >> 6) * 16 + (q & 15);
    int k = ((q >> 4) & 3) * 8;
    so[s] = row * K_DIM + k;
    dof[s] = (s * 512 + wv * 64) * 8;  // u16 units
  }

  // Frag reads: A subtile (wr*8 + mi) at chunk base ((wr*8+mi)*64)*8 u16;
  // B subtile (wc*4 + ni) likewise. Lane offset l8 -> contiguous 1KB/wave.
#define LDA(b, m) (*(const bf16x8*)(&Alds[b][wr * 4096 + (m) * 512 + l8]))
#define LDB(b, n) (*(const bf16x8*)(&Blds[b][wc * 2048 + (n) * 512 + l8]))

  f32x4 acc[8][4];
#pragma unroll
  for (int mi = 0; mi < 8; ++mi)
#pragma unroll
    for (int ni = 0; ni < 4; ++ni)
      acc[mi][ni] = (f32x4){0.f, 0.f, 0.f, 0.f};

  // stage K-tile g into ring buffer g&3 (A: 2 gloads; B: 2 gloads per thread)
  auto stageA = [&](int g) {
    if (g < NT) {
      const u16* src = Ag + g * 32;
      gload16(src + so[0], &Alds[g & 3][dof[0]]);
      gload16(src + so[1], &Alds[g & 3][dof[1]]);
    }
  };
  auto stageB = [&](int g) {
    if (g < NT) {
      const u16* src = Bg + g * 32;
      gload16(src + so[0], &Blds[g & 3][dof[0]]);
      gload16(src + so[1], &Blds[g & 3][dof[1]]);
    }
  };

#define MFMA4(m0, m1, n0, n1, aset, bset)                                      \
  acc[m0][n0] = MFMA(aset[0], bset[0], acc[m0][n0]);                           \
  acc[m0][n1] = MFMA(aset[0], bset[1], acc[m0][n1]);                           \
  acc[m1][n0] = MFMA(aset[1], bset[0], acc[m1][n0]);                           \
  acc[m1][n1] = MFMA(aset[1], bset[1], acc[m1][n1])

  // one K-tile; b = kt&3 compile-time at each expansion
#define K_TILE(kt, b)                                                          \
  {                                                                            \
    bf16x8 a01[2], a23[2], a45[2], a67[2], b01[2], b23[2];                     \
    /* pre: A0,A1,B0,B1 */                                                     \
    a01[0] = LDA(b, 0); a01[1] = LDA(b, 1);                                    \
    b01[0] = LDB(b, 0); b01[1] = LDB(b, 1);                                    \
    SGB(0x100, 4);                                                             \
    /* b0: R{A2,A3,B2}; stage A(kt+3); M{A01 x B01} */                         \
    a23[0] = LDA(b, 2); a23[1] = LDA(b, 3);                                    \
    b23[0] = LDB(b, 2);                                                        \
    stageA((kt) + 3);                                                          \
    MFMA4(0, 1, 0, 1, a01, b01);                                               \
    SGB(0x100, 3); SGB(0x20, 2); SGB(0x8, 4);                                  \
    /* b1: R{A4,A5,B3}; stage B(kt+3); M{A23 x B01} */                         \
    a45[0] = LDA(b, 4); a45[1] = LDA(b, 5);                                    \
    b23[1] = LDB(b, 3);                                                        \
    stageB((kt) + 3);                                                          \
    MFMA4(2, 3, 0, 1, a23, b01);                                               \
    SGB(0x100, 3); SGB(0x20, 2); SGB(0x8, 4);                                  \
    /* b2: R{A6,A7}; M{A01 x B23} */                                           \
    a67[0] = LDA(b, 6); a67[1] = LDA(b, 7);                                    \
    MFMA4(0, 1, 2, 3, a01, b23);                                               \
    SGB(0x100, 2); SGB(0x8, 4);                                                \
    /* b3-b7: remaining MFMA quads */                                          \
    MFMA4(2, 3, 2, 3, a23, b23);                                               \
    SGB(0x8, 4);                                                               \
    MFMA4(4, 5, 0, 1, a45, b01);                                               \
    SGB(0x8, 4);                                                               \
    MFMA4(4, 5, 2, 3, a45, b23);                                               \
    SGB(0x8, 4);                                                               \
    MFMA4(6, 7, 0, 1, a67, b01);                                               \
    SGB(0x8, 4);                                                               \
    MFMA4(6, 7, 2, 3, a67, b23);                                               \
    SGB(0x8, 4);                                                               \
    /* tile end: counted wait -- only tile kt+1's loads must be done */        \
    if ((kt) < NT - 3) {                                                       \
      asm volatile("s_waitcnt vmcnt(8)" ::: "memory");                         \
      __builtin_amdgcn_s_barrier();                                            \
    } else if ((kt) == NT - 3) {                                               \
      asm volatile("s_waitcnt vmcnt(4)" ::: "memory");                         \
      __builtin_amdgcn_s_barrier();                                            \
    } else if ((kt) == NT - 2) {                                               \
      asm volatile("s_waitcnt vmcnt(0)" ::: "memory");                         \
      __builtin_amdgcn_s_barrier();                                            \
    } /* last tile: no wait, epilogue follows */                               \
  }

  // prologue: stage tiles 0,1,2 (12 loads); wait for tile 0's 4 (vmcnt(8))
  stageA(0); stageB(0);
  stageA(1); stageB(1);
  stageA(2); stageB(2);
  asm volatile("s_waitcnt vmcnt(8)" ::: "memory");
  __builtin_amdgcn_s_barrier();

  for (int kt4 = 0; kt4 < NT; kt4 += 4) {
    K_TILE(kt4 + 0, 0);
    K_TILE(kt4 + 1, 1);
    K_TILE(kt4 + 2, 2);
    K_TILE(kt4 + 3, 3);
  }
#undef K_TILE
#undef MFMA4
#undef LDA
#undef LDB

  // epilogue: y = alpha*acc + bias.  C/D: col=l&15, row=4*(l>>4)+j (m89-verified)
  const float alpha = alpha_f[0];
#pragma unroll
  for (int ni = 0; ni < 4; ++ni) {
    const int col = tn * 256 + wc * 64 + ni * 16 + lr;
    const float bs = bias[col];
#pragma unroll
    for (int mi = 0; mi < 8; ++mi) {
      const int row = tm * 256 + wr * 128 + mi * 16 + lk * 4;
      float* Cp = C + (size_t)row * N_DIM + col;
#pragma unroll
      for (int j = 0; j < 4; ++j)
        Cp[(size_t)j * N_DIM] = alpha * acc[mi][ni][j] + bs;
    }
  }
}

extern "C" void kernel_launch(void* const* d_in, const int* in_sizes, int n_in,
                              void* d_out, int out_size, void* d_ws, size_t ws_size,
                              hipStream_t stream) {
  const float* x = (const float*)d_in[0];
  const float* w = (const float*)d_in[1];
  const float* bias = (const float*)d_in[2];
  float* out = (float*)d_out;

  char* ws = (char*)d_ws;
  double* alpha_d = (double*)ws;
  float* alpha_f = (float*)(ws + 8);
  double* partials = (double*)(ws + 16);
  u16* xb = (u16*)(ws + 65536);                 // 64 MiB (M*K bf16)
  u16* qb = (u16*)(ws + 65536 + 67108864ULL);   // 128 MiB (N*K bf16)

  reduce_abs1<<<4096, 256, 0, stream>>>(w, partials);
  reduce_abs2<<<1, 256, 0, stream>>>(partials, alpha_d, alpha_f);
  quant_w<<<32768, 256, 0, stream>>>(w, alpha_d, qb);
  conv_x<<<16384, 256, 0, stream>>>(x, xb);
  gemm256<<<2048, 512, 0, stream>>>(xb, qb, bias, alpha_f, out);
}

// Round 13
// 1130.772 us; speedup vs baseline: 1.1944x; 1.1944x over previous
//
#include <hip/hip_runtime.h>

// y = alpha*(x @ Q^T) + bias; alpha = mean|W|; Q = clip(round(W/alpha),-1,1)
// x:(2,4096,4096) f32, W:(16384,4096) f32, bias:(16384) f32, out f32.
#define M_DIM 8192
#define N_DIM 16384
#define K_DIM 4096
#define NT 128  // K_DIM / 32

typedef unsigned short u16;
typedef unsigned int u32;
typedef __attribute__((ext_vector_type(8))) short bf16x8;
typedef __attribute__((ext_vector_type(8))) unsigned short u16x8;
typedef __attribute__((ext_vector_type(4))) float f32x4;

#define MFMA(a, b, c) __builtin_amdgcn_mfma_f32_16x16x32_bf16(a, b, c, 0, 0, 0)
#define SGB(mask, n) __builtin_amdgcn_sched_group_barrier((mask), (n), 0)

__device__ __forceinline__ void gload16(const u16* g, u16* l) {
  __builtin_amdgcn_global_load_lds((const __attribute__((address_space(1))) void*)g,
                                   (__attribute__((address_space(3))) void*)l, 16, 0, 0);
}

// ---------------- alpha = mean(|W|), f64 two-pass reduction ----------------
__global__ void reduce_abs1(const float* __restrict__ w, double* __restrict__ partials) {
  const float4* w4 = (const float4*)w;
  size_t base = (size_t)blockIdx.x * 4096 + threadIdx.x;
  double s = 0.0;
#pragma unroll
  for (int i = 0; i < 16; ++i) {
    float4 v = w4[base + (size_t)i * 256];
    s += (double)fabsf(v.x); s += (double)fabsf(v.y);
    s += (double)fabsf(v.z); s += (double)fabsf(v.w);
  }
#pragma unroll
  for (int off = 32; off > 0; off >>= 1) s += __shfl_down(s, off, 64);
  __shared__ double red[4];
  int wv = threadIdx.x >> 6, lane = threadIdx.x & 63;
  if (lane == 0) red[wv] = s;
  __syncthreads();
  if (threadIdx.x == 0) partials[blockIdx.x] = (red[0] + red[1]) + (red[2] + red[3]);
}

__global__ void reduce_abs2(const double* __restrict__ partials,
                            double* __restrict__ alpha_d, float* __restrict__ alpha_f) {
  double s = 0.0;
  for (int i = threadIdx.x; i < 4096; i += 256) s += partials[i];
#pragma unroll
  for (int off = 32; off > 0; off >>= 1) s += __shfl_down(s, off, 64);
  __shared__ double red[4];
  int wv = threadIdx.x >> 6, lane = threadIdx.x & 63;
  if (lane == 0) red[wv] = s;
  __syncthreads();
  if (threadIdx.x == 0) {
    double total = (red[0] + red[1]) + (red[2] + red[3]);
    double a = total / (double)((long long)N_DIM * (long long)K_DIM);
    alpha_d[0] = a;
    alpha_f[0] = (float)a;
  }
}

// ---------------- W -> ternary Q stored as bf16 (+1/0/-1 exact) ----------------
__global__ void quant_w(const float* __restrict__ w, const double* __restrict__ alpha_d,
                        u16* __restrict__ q) {
  double inv = 1.0 / alpha_d[0];
  size_t i8 = (size_t)blockIdx.x * 256 + threadIdx.x;
  const float4* w4 = (const float4*)w;
  float4 v0 = w4[i8 * 2], v1 = w4[i8 * 2 + 1];
  float vv[8] = {v0.x, v0.y, v0.z, v0.w, v1.x, v1.y, v1.z, v1.w};
  u16x8 o;
#pragma unroll
  for (int j = 0; j < 8; ++j) {
    double r = rint((double)vv[j] * inv);
    u16 enc = 0;
    if (r >= 1.0) enc = 0x3F80u;
    else if (r <= -1.0) enc = 0xBF80u;
    o[j] = enc;
  }
  *((u16x8*)q + i8) = o;
}

// ---------------- x fp32 -> bf16 (RNE) ----------------
__global__ void conv_x(const float* __restrict__ x, u16* __restrict__ xb) {
  size_t i8 = (size_t)blockIdx.x * 256 + threadIdx.x;
  const float4* x4 = (const float4*)x;
  float4 v0 = x4[i8 * 2], v1 = x4[i8 * 2 + 1];
  float vv[8] = {v0.x, v0.y, v0.z, v0.w, v1.x, v1.y, v1.z, v1.w};
  u16x8 o;
#pragma unroll
  for (int j = 0; j < 8; ++j) {
    u32 u = __float_as_uint(vv[j]);
    u += 0x7FFFu + ((u >> 16) & 1u);
    o[j] = (u16)(u >> 16);
  }
  *((u16x8*)xb + i8) = o;
}

// --- 256x256-tile bf16 GEMM: BK=32 ring-4, counted vmcnt, FIXED XOR swizzle ---
// R11 structure verbatim; single change: the BK=32 swizzle bit. R11 used
// c = lk ^ (row&3): among even rows (bank-half 0) row&3 only hits {0,2} ->
// 4 lanes pile per bank-quad -> ~4-way conflicts (SQ_LDS_BANK_CONFLICT
// 1.007e8 ~= 16% of runtime). Fix: c = lk ^ ((row>>1)&3) -> over the 8
// even rows the XOR key covers 0..3 exactly twice -> uniform 8 dword-accesses
// per bank (the b128 minimum), same uniformity as R8's proven BK=64 swizzle.
// Involution on both sides (pre-swizzled global source + swizzled read);
// sub-tile bases still fold to immediates ((row>>1)&3 == (lr>>1)&3 since all
// sub offsets are multiples of 8 rows). T4 counted vmcnt(8) ring-4 kept;
// SGB batches kept; no setprio (R10 -7%); no intra-tile barriers (R6).
__global__ __launch_bounds__(512, 2) void gemm256(
    const u16* __restrict__ A, const u16* __restrict__ Bq,
    const float* __restrict__ bias, const float* __restrict__ alpha_f,
    float* __restrict__ C) {
  __shared__ __align__(16) u16 Alds[4][256 * 32];  // 16 KiB per ring buffer
  __shared__ __align__(16) u16 Blds[4][256 * 32];

  const int t = threadIdx.x;
  const int wv = t >> 6, l = t & 63;
  const int wr = wv >> 2, wc = wv & 3;  // 2M x 4N wave grid
  const int lr = l & 15, lk = l >> 4;

  // XCD-bijective swizzle (2048 % 8 == 0) + 8(tm) x 64(tn) supertiles
  const int bid = blockIdx.x;
  const int wg = (bid & 7) * 256 + (bid >> 3);
  const int grp = wg >> 9, rem = wg & 511;
  const int tm = grp * 8 + (rem & 7);  // 0..31
  const int tn = rem >> 3;             // 0..63

  const u16* Ag = A + (size_t)tm * 256 * K_DIM;
  const u16* Bg = Bq + (size_t)tn * 256 * K_DIM;

  // Staging: 16B chunk q in [0,1024) of a [256][32] tile: row=q>>2, physical
  // chunk pc=q&3 holds logical chunk c = pc ^ ((row>>1)&3) (involution; read
  // applies the same XOR). LDS dest linear (wave-uniform base + lane*16).
  int so[2], dof[2];
#pragma unroll
  for (int s = 0; s < 2; ++s) {
    int q = s * 512 + t;
    int row = q >> 2, c = (q & 3) ^ ((row >> 1) & 3);
    so[s] = row * K_DIM + c * 8;
    dof[s] = (s * 512 + wv * 64) * 8;  // u16 units
  }

  // Frag read base (u16): row = sub*16 + lr, chunk lk^((lr>>1)&3);
  // per-sub offset sub*512 folds to an immediate.
  const int fb = lr * 32 + ((lk ^ ((lr >> 1) & 3)) * 8);
#define LDA(b, m) (*(const bf16x8*)(&Alds[b][wr * 4096 + (m) * 512 + fb]))
#define LDB(b, n) (*(const bf16x8*)(&Blds[b][wc * 2048 + (n) * 512 + fb]))

  f32x4 acc[8][4];
#pragma unroll
  for (int mi = 0; mi < 8; ++mi)
#pragma unroll
    for (int ni = 0; ni < 4; ++ni)
      acc[mi][ni] = (f32x4){0.f, 0.f, 0.f, 0.f};

  // stage K-tile g into ring buffer g&3 (A: 2 gloads; B: 2 gloads per thread)
  auto stageA = [&](int g) {
    if (g < NT) {
      const u16* src = Ag + g * 32;
      gload16(src + so[0], &Alds[g & 3][dof[0]]);
      gload16(src + so[1], &Alds[g & 3][dof[1]]);
    }
  };
  auto stageB = [&](int g) {
    if (g < NT) {
      const u16* src = Bg + g * 32;
      gload16(src + so[0], &Blds[g & 3][dof[0]]);
      gload16(src + so[1], &Blds[g & 3][dof[1]]);
    }
  };

#define MFMA4(m0, m1, n0, n1, aset, bset)                                      \
  acc[m0][n0] = MFMA(aset[0], bset[0], acc[m0][n0]);                           \
  acc[m0][n1] = MFMA(aset[0], bset[1], acc[m0][n1]);                           \
  acc[m1][n0] = MFMA(aset[1], bset[0], acc[m1][n0]);                           \
  acc[m1][n1] = MFMA(aset[1], bset[1], acc[m1][n1])

  // one K-tile; b = kt&3 compile-time at each expansion
#define K_TILE(kt, b)                                                          \
  {                                                                            \
    bf16x8 a01[2], a23[2], a45[2], a67[2], b01[2], b23[2];                     \
    /* pre: A0,A1,B0,B1 */                                                     \
    a01[0] = LDA(b, 0); a01[1] = LDA(b, 1);                                    \
    b01[0] = LDB(b, 0); b01[1] = LDB(b, 1);                                    \
    SGB(0x100, 4);                                                             \
    /* b0: R{A2,A3,B2}; stage A(kt+3); M{A01 x B01} */                         \
    a23[0] = LDA(b, 2); a23[1] = LDA(b, 3);                                    \
    b23[0] = LDB(b, 2);                                                        \
    stageA((kt) + 3);                                                          \
    MFMA4(0, 1, 0, 1, a01, b01);                                               \
    SGB(0x100, 3); SGB(0x20, 2); SGB(0x8, 4);                                  \
    /* b1: R{A4,A5,B3}; stage B(kt+3); M{A23 x B01} */                         \
    a45[0] = LDA(b, 4); a45[1] = LDA(b, 5);                                    \
    b23[1] = LDB(b, 3);                                                        \
    stageB((kt) + 3);                                                          \
    MFMA4(2, 3, 0, 1, a23, b01);                                               \
    SGB(0x100, 3); SGB(0x20, 2); SGB(0x8, 4);                                  \
    /* b2: R{A6,A7}; M{A01 x B23} */                                           \
    a67[0] = LDA(b, 6); a67[1] = LDA(b, 7);                                    \
    MFMA4(0, 1, 2, 3, a01, b23);                                               \
    SGB(0x100, 2); SGB(0x8, 4);                                                \
    /* b3-b7: remaining MFMA quads */                                          \
    MFMA4(2, 3, 2, 3, a23, b23);                                               \
    SGB(0x8, 4);                                                               \
    MFMA4(4, 5, 0, 1, a45, b01);                                               \
    SGB(0x8, 4);                                                               \
    MFMA4(4, 5, 2, 3, a45, b23);                                               \
    SGB(0x8, 4);                                                               \
    MFMA4(6, 7, 0, 1, a67, b01);                                               \
    SGB(0x8, 4);                                                               \
    MFMA4(6, 7, 2, 3, a67, b23);                                               \
    SGB(0x8, 4);                                                               \
    /* tile end: counted wait -- only tile kt+1's loads must be done */        \
    if ((kt) < NT - 3) {                                                       \
      asm volatile("s_waitcnt vmcnt(8)" ::: "memory");                         \
      __builtin_amdgcn_s_barrier();                                            \
    } else if ((kt) == NT - 3) {                                               \
      asm volatile("s_waitcnt vmcnt(4)" ::: "memory");                         \
      __builtin_amdgcn_s_barrier();                                            \
    } else if ((kt) == NT - 2) {                                               \
      asm volatile("s_waitcnt vmcnt(0)" ::: "memory");                         \
      __builtin_amdgcn_s_barrier();                                            \
    } /* last tile: no wait, epilogue follows */                               \
  }

  // prologue: stage tiles 0,1,2 (12 loads); wait for tile 0's 4 (vmcnt(8))
  stageA(0); stageB(0);
  stageA(1); stageB(1);
  stageA(2); stageB(2);
  asm volatile("s_waitcnt vmcnt(8)" ::: "memory");
  __builtin_amdgcn_s_barrier();

  for (int kt4 = 0; kt4 < NT; kt4 += 4) {
    K_TILE(kt4 + 0, 0);
    K_TILE(kt4 + 1, 1);
    K_TILE(kt4 + 2, 2);
    K_TILE(kt4 + 3, 3);
  }
#undef K_TILE
#undef MFMA4
#undef LDA
#undef LDB

  // epilogue: y = alpha*acc + bias.  C/D: col=l&15, row=4*(l>>4)+j (m89-verified)
  const float alpha = alpha_f[0];
#pragma unroll
  for (int ni = 0; ni < 4; ++ni) {
    const int col = tn * 256 + wc * 64 + ni * 16 + lr;
    const float bs = bias[col];
#pragma unroll
    for (int mi = 0; mi < 8; ++mi) {
      const int row = tm * 256 + wr * 128 + mi * 16 + lk * 4;
      float* Cp = C + (size_t)row * N_DIM + col;
#pragma unroll
      for (int j = 0; j < 4; ++j)
        Cp[(size_t)j * N_DIM] = alpha * acc[mi][ni][j] + bs;
    }
  }
}

extern "C" void kernel_launch(void* const* d_in, const int* in_sizes, int n_in,
                              void* d_out, int out_size, void* d_ws, size_t ws_size,
                              hipStream_t stream) {
  const float* x = (const float*)d_in[0];
  const float* w = (const float*)d_in[1];
  const float* bias = (const float*)d_in[2];
  float* out = (float*)d_out;

  char* ws = (char*)d_ws;
  double* alpha_d = (double*)ws;
  float* alpha_f = (float*)(ws + 8);
  double* partials = (double*)(ws + 16);
  u16* xb = (u16*)(ws + 65536);                 // 64 MiB (M*K bf16)
  u16* qb = (u16*)(ws + 65536 + 67108864ULL);   // 128 MiB (N*K bf16)

  reduce_abs1<<<4096, 256, 0, stream>>>(w, partials);
  reduce_abs2<<<1, 256, 0, stream>>>(partials, alpha_d, alpha_f);
  quant_w<<<32768, 256, 0, stream>>>(w, alpha_d, qb);
  conv_x<<<16384, 256, 0, stream>>>(x, xb);
  gemm256<<<2048, 512, 0, stream>>>(xb, qb, bias, alpha_f, out);
}